// Round 11
// baseline (2797.468 us; speedup 1.0000x reference)
//
#include <hip/hip_runtime.h>

#define LSEQ 2048
#define NB 24
#define NH 75
#define G3 225
#define NIN 500
#define OUTW 450
#define NRING 32
#define RINGSTRIDE (96 * 225)  // floats per ring slot: 4 cells x 24 batches x 225 rows

typedef _Float16 h2 __attribute__((ext_vector_type(2)));
typedef _Float16 h8 __attribute__((ext_vector_type(8)));
typedef float f4 __attribute__((ext_vector_type(4)));

__device__ __forceinline__ h2 pkrtz(float a, float b) {
  return __builtin_bit_cast(h2, __builtin_amdgcn_cvt_pkrtz(a, b));
}
__device__ __forceinline__ float dot2(h2 a, h2 b, float c) {
  return __builtin_amdgcn_fdot2(a, b, c, false);
}
__device__ __forceinline__ float dot8(h8 w, h8 x, float c) {
  h2 w0{w[0], w[1]}, w1{w[2], w[3]}, w2{w[4], w[5]}, w3{w[6], w[7]};
  h2 x0{x[0], x[1]}, x1{x[2], x[3]}, x2{x[4], x[5]}, x3{x[6], x[7]};
  c = dot2(w0, x0, c);
  c = dot2(w1, x1, c);
  c = dot2(w2, x2, c);
  c = dot2(w3, x3, c);
  return c;
}
__device__ __forceinline__ h8 ld8f(const float* p, int base, int n) {
  h8 o;
#pragma unroll
  for (int i = 0; i < 8; i += 2) {
    float a = (base + i < n) ? p[base + i] : 0.f;
    float b = (base + i + 1 < n) ? p[base + i + 1] : 0.f;
    h2 t = pkrtz(a, b);
    o[i] = t[0];
    o[i + 1] = t[1];
  }
  return o;
}
__device__ __forceinline__ h8 zero8() {
  h8 v;
#pragma unroll
  for (int i = 0; i < 8; i++) v[i] = (_Float16)0;
  return v;
}
__device__ __forceinline__ float sigm(float x) {
  return __builtin_amdgcn_rcpf(1.f + __builtin_amdgcn_exp2f(-1.4426950408889634f * x));
}
__device__ __forceinline__ float tanh_f(float x) {
  float xx = fminf(x, 15.f);
  float e = __builtin_amdgcn_exp2f(2.8853900817779268f * xx);
  return (e - 1.f) * __builtin_amdgcn_rcpf(e + 1.f);
}

// device-scope relaxed (sc1)
__device__ __forceinline__ float ldg_dev(const float* p) {
  return __hip_atomic_load(p, __ATOMIC_RELAXED, __HIP_MEMORY_SCOPE_AGENT);
}
__device__ __forceinline__ void stg_dev(float* p, float v) {
  __hip_atomic_store(p, v, __ATOMIC_RELAXED, __HIP_MEMORY_SCOPE_AGENT);
}
__device__ __forceinline__ int ldflag(const int* p) {
  return __hip_atomic_load(p, __ATOMIC_RELAXED, __HIP_MEMORY_SCOPE_AGENT);
}
__device__ __forceinline__ void stflag(int* p, int v) {
  __hip_atomic_store(p, v, __ATOMIC_RELAXED, __HIP_MEMORY_SCOPE_AGENT);
}

#define PIN4(a, b, c, d) asm("" : "+v"(a), "+v"(b), "+v"(c), "+v"(d))
#define PIN2(a, b) asm("" : "+v"(a), "+v"(b))

// Raw workgroup barrier: lgkm-only drain; vmem stays in flight (rule #18 fences).
#define WG_BARRIER()                                     \
  do {                                                   \
    asm volatile("s_waitcnt lgkmcnt(0)" ::: "memory");   \
    __builtin_amdgcn_sched_barrier(0);                   \
    __builtin_amdgcn_s_barrier();                        \
    __builtin_amdgcn_sched_barrier(0);                   \
  } while (0)

// ---------------- init flags ----------------
// flags[0..143]   : scan progress per (cell c, b): v => h(times <= v-1) stored.
// flags[144..239] : helper A availability per (cell c>=2, b): v => A(times <= v-1) stored.
__global__ void init_flags(int* f) {
  if (threadIdx.x < 240) stflag(&f[threadIdx.x], 0);
}

// ---------------- kernel A: gx GEMM (unchanged, it works) ----------------
__device__ __forceinline__ void load8_guard(float* v, const float* src, int kbase, bool rowvalid) {
  if (rowvalid && (kbase + 8 <= NIN)) {
    f4 t0 = *(const f4*)(src);
    f4 t1 = *(const f4*)(src + 4);
    v[0] = t0[0]; v[1] = t0[1]; v[2] = t0[2]; v[3] = t0[3];
    v[4] = t1[0]; v[5] = t1[1]; v[6] = t1[2]; v[7] = t1[3];
  } else {
#pragma unroll
    for (int i = 0; i < 8; i++) v[i] = (rowvalid && (kbase + i < NIN)) ? src[i] : 0.f;
  }
}
__device__ __forceinline__ void pack8_store(_Float16* dst, const float* v) {
  h2 a = pkrtz(v[0], v[1]);
  h2 b = pkrtz(v[2], v[3]);
  h2 c = pkrtz(v[4], v[5]);
  h2 d = pkrtz(v[6], v[7]);
  h8 o;
  o[0] = a[0]; o[1] = a[1]; o[2] = b[0]; o[3] = b[1];
  o[4] = c[0]; o[5] = c[1]; o[6] = d[0]; o[7] = d[1];
  *(h8*)dst = o;
}

__global__ __launch_bounds__(256) void gemm_gx(const float* __restrict__ x,
                                               const float* __restrict__ w,
                                               const float* __restrict__ bias,
                                               float* __restrict__ out) {
  __shared__ __align__(16) _Float16 xs[64 * 40];
  __shared__ __align__(16) _Float16 wsh[464 * 40];
  const int tid = threadIdx.x;
  const int blk = blockIdx.x;
  const int lane = tid & 63, wid = tid >> 6;
  const int q = lane >> 4, cn = lane & 15;
  const int r = tid >> 2, kq = tid & 3;

  f4 acc[29];
#pragma unroll
  for (int j = 0; j < 29; j++) acc[j] = f4{0.f, 0.f, 0.f, 0.f};

  for (int kc = 0; kc < 16; kc++) {
    const int kbase = kc * 32 + kq * 8;
    {
      const float* src = x + (size_t)(blk * 64 + r) * NIN + kbase;
      float v[8];
      load8_guard(v, src, kbase, true);
      pack8_store(&xs[r * 40 + kq * 8], v);
    }
#pragma unroll
    for (int it = 0; it < 8; it++) {
      int rr = r + it * 64;
      if (rr < 464) {
        const float* src = w + (size_t)rr * NIN + kbase;
        float v[8];
        load8_guard(v, src, kbase, rr < OUTW);
        pack8_store(&wsh[rr * 40 + kq * 8], v);
      }
    }
    __syncthreads();
    h8 a = *(const h8*)&xs[(wid * 16 + cn) * 40 + q * 8];
#pragma unroll
    for (int j = 0; j < 29; j++) {
      h8 bf = *(const h8*)&wsh[(j * 16 + cn) * 40 + q * 8];
      acc[j] = __builtin_amdgcn_mfma_f32_16x16x32_f16(a, bf, acc[j], 0, 0, 0);
    }
    __syncthreads();
  }
#pragma unroll
  for (int j = 0; j < 29; j++) {
    int n = j * 16 + cn;
    float bv = (n < OUTW) ? bias[n] : 0.f;
#pragma unroll
    for (int rr = 0; rr < 4; rr++) {
      float val = acc[j][rr] + bv;
      float partner = __shfl_xor(val, 1, 64);
      if (((lane & 1) == 0) && n < OUTW) {
        h2 pk = pkrtz(val, partner);
        int mg = blk * 64 + wid * 16 + q * 4 + rr;
        out[(size_t)mg * OUTW + G3 + (n >> 1)] = __builtin_bit_cast(float, pk);
      }
    }
  }
}

// ---------------- kernel B: scan (144 WGs) + U.x helpers (96 WGs) ----------------
// R11: WHOLE-ELEMENT-PER-LANE scan. Lane j owns rows {j, 75+j, 150+j} = the
// r/z/n gates of h[j]: dots -> gates -> activation -> h[j] all in-register.
// Deletes A_s/B_s LDS round-trip, barrier1, and the P1->P2 cross-wave handoff
// (R5..R10's invariant ~2800cy step floor). ONE barrier/step; h broadcast via
// double-buffered h16[2][80]. Per-row accumulation order and fp32 A values
// unchanged -> bitwise-identical output. 6 independent dot half-chains/lane
// (3 gates x a/b) give 6-way ILP on the former 2-chain critical path.
// Helper role (U.x producer) unchanged from R10.
__global__ __launch_bounds__(256, 1) __attribute__((amdgpu_waves_per_eu(1)))
void scan_gru(const float* __restrict__ h0,
              const float* __restrict__ w_hh0, const float* __restrict__ b_hh0,
              const float* __restrict__ w_ih12, const float* __restrict__ w_hh12,
              const float* __restrict__ b_ih12, const float* __restrict__ b_hh12,
              float* __restrict__ out, int* flags) {
  __shared__ __align__(16) _Float16 h16[2][80];
  __shared__ __align__(16) _Float16 xs[2][152];  // helper x staging

  float* Aring = (float*)(flags + 256);
  const int tid = threadIdx.x;
  const int bi = blockIdx.x;

  if (bi < 144) {
    // ================= SCAN ROLE =================
    const int c = bi / NB, b = bi % NB;
    const int l = c >> 1, d = c & 1;
    const int ci = (l - 1) * 2 + d;
    const int j = tid;
    const bool act = (tid < NH);

    // weights: 3 rows per lane (r=j, z=75+j, n=150+j)
    h8 WR0 = zero8(), WR1 = zero8(), WR2 = zero8(), WR3 = zero8(), WR4 = zero8();
    h8 WR5 = zero8(), WR6 = zero8(), WR7 = zero8(), WR8 = zero8(), WR9 = zero8();
    h8 WZ0 = zero8(), WZ1 = zero8(), WZ2 = zero8(), WZ3 = zero8(), WZ4 = zero8();
    h8 WZ5 = zero8(), WZ6 = zero8(), WZ7 = zero8(), WZ8 = zero8(), WZ9 = zero8();
    h8 WN0 = zero8(), WN1 = zero8(), WN2 = zero8(), WN3 = zero8(), WN4 = zero8();
    h8 WN5 = zero8(), WN6 = zero8(), WN7 = zero8(), WN8 = zero8(), WN9 = zero8();
    float bhR = 0.f, bhZ = 0.f, bhN = 0.f;
    if (act) {
      const float* base = (l == 0) ? w_hh0 + (size_t)(d * G3) * NH
                                   : w_hh12 + (size_t)(ci * G3) * NH;
      const float* wR = base + (size_t)j * NH;
      const float* wZ = base + (size_t)(NH + j) * NH;
      const float* wN = base + (size_t)(2 * NH + j) * NH;
      WR0 = ld8f(wR, 0, NH);  WR1 = ld8f(wR, 8, NH);  WR2 = ld8f(wR, 16, NH);
      WR3 = ld8f(wR, 24, NH); WR4 = ld8f(wR, 32, NH); WR5 = ld8f(wR, 40, NH);
      WR6 = ld8f(wR, 48, NH); WR7 = ld8f(wR, 56, NH); WR8 = ld8f(wR, 64, NH);
      WR9 = ld8f(wR, 72, NH);
      WZ0 = ld8f(wZ, 0, NH);  WZ1 = ld8f(wZ, 8, NH);  WZ2 = ld8f(wZ, 16, NH);
      WZ3 = ld8f(wZ, 24, NH); WZ4 = ld8f(wZ, 32, NH); WZ5 = ld8f(wZ, 40, NH);
      WZ6 = ld8f(wZ, 48, NH); WZ7 = ld8f(wZ, 56, NH); WZ8 = ld8f(wZ, 64, NH);
      WZ9 = ld8f(wZ, 72, NH);
      WN0 = ld8f(wN, 0, NH);  WN1 = ld8f(wN, 8, NH);  WN2 = ld8f(wN, 16, NH);
      WN3 = ld8f(wN, 24, NH); WN4 = ld8f(wN, 32, NH); WN5 = ld8f(wN, 40, NH);
      WN6 = ld8f(wN, 48, NH); WN7 = ld8f(wN, 56, NH); WN8 = ld8f(wN, 64, NH);
      WN9 = ld8f(wN, 72, NH);
      const float* bb = (l == 0) ? b_hh0 + d * G3 : b_hh12 + ci * G3;
      bhR = bb[j]; bhZ = bb[NH + j]; bhN = bb[2 * NH + j];
    }

    float hreg = 0.f, hh0 = 0.f, hh1 = 0.f, hh2 = 0.f;
    if (act) {
      hreg = h0[(size_t)(c * NB + b) * NH + j];
      h16[0][j] = (_Float16)hreg;
    }
    if (tid >= NH && tid < 80) { h16[0][tid] = (_Float16)0; h16[1][tid] = (_Float16)0; }

    // l0: loop-carried gx dwords for rows j, 75+j, 150+j
    const int n0r = d * G3 + j, n0z = n0r + NH, n0n = n0r + 2 * NH;
    float cr0 = 0.f, cr1 = 0.f, cr2 = 0.f;
    if (l == 0 && act) {
      const float* row = out + (size_t)b * OUTW + G3;
      cr0 = row[n0r >> 1]; cr1 = row[n0z >> 1]; cr2 = row[n0n >> 1];
    }

    // l>=1: loop-carried A values (fp32 ring)
    const int* fHp = (l > 0) ? &flags[144 + (c - 2) * NB + b] : flags;
    const int abase = (c - 2) * NB + b;
    int fvH = 0;
    float ar0 = 0.f, ar1 = 0.f, ar2 = 0.f;
    if (l > 0 && act) {
      while (ldflag(fHp) < 5) {}
      const float* slot0 = &Aring[(size_t)abase * 225 + j];
      ar0 = ldg_dev(slot0);
      ar1 = ldg_dev(slot0 + NH);
      ar2 = ldg_dev(slot0 + 2 * NH);
      fvH = 5;
    }
    __syncthreads();

    for (int t = 0; t < LSEQ; t++) {
      if (act) {
        PIN4(WR0, WR1, WR2, WR3); PIN4(WR4, WR5, WR6, WR7); PIN2(WR8, WR9);
        PIN4(WZ0, WZ1, WZ2, WZ3); PIN4(WZ4, WZ5, WZ6, WZ7); PIN2(WZ8, WZ9);
        PIN4(WN0, WN1, WN2, WN3); PIN4(WN4, WN5, WN6, WN7); PIN2(WN8, WN9);
        const h8* hv = (const h8*)h16[t & 1];
        h8 H0 = hv[0], H1 = hv[1], H2 = hv[2], H3 = hv[3], H4 = hv[4];
        h8 H5 = hv[5], H6 = hv[6], H7 = hv[7], H8 = hv[8], H9 = hv[9];
        // three rows, identical per-row chain order as before (a/b split):
        float ra = dot8(WR0, H0, bhR), rb = dot8(WR1, H1, 0.f);
        ra = dot8(WR2, H2, ra); rb = dot8(WR3, H3, rb);
        ra = dot8(WR4, H4, ra); rb = dot8(WR5, H5, rb);
        ra = dot8(WR6, H6, ra); rb = dot8(WR7, H7, rb);
        ra = dot8(WR8, H8, ra); rb = dot8(WR9, H9, rb);
        float za = dot8(WZ0, H0, bhZ), zb = dot8(WZ1, H1, 0.f);
        za = dot8(WZ2, H2, za); zb = dot8(WZ3, H3, zb);
        za = dot8(WZ4, H4, za); zb = dot8(WZ5, H5, zb);
        za = dot8(WZ6, H6, za); zb = dot8(WZ7, H7, zb);
        za = dot8(WZ8, H8, za); zb = dot8(WZ9, H9, zb);
        float na = dot8(WN0, H0, bhN), nb = dot8(WN1, H1, 0.f);
        na = dot8(WN2, H2, na); nb = dot8(WN3, H3, nb);
        na = dot8(WN4, H4, na); nb = dot8(WN5, H5, nb);
        na = dot8(WN6, H6, na); nb = dot8(WN7, H7, nb);
        na = dot8(WN8, H8, na); nb = dot8(WN9, H9, nb);
        float Br = ra + rb, Bz = za + zb, Bn = na + nb;

        float Ar, Az, An;
        if (l == 0) {
          h2 p0 = __builtin_bit_cast(h2, cr0);
          h2 p1 = __builtin_bit_cast(h2, cr1);
          h2 p2 = __builtin_bit_cast(h2, cr2);
          Ar = (n0r & 1) ? (float)p0[1] : (float)p0[0];
          Az = (n0z & 1) ? (float)p1[1] : (float)p1[0];
          An = (n0n & 1) ? (float)p2[1] : (float)p2[0];
          if (t + 1 < LSEQ) {
            const float* row = out + ((size_t)(t + 1) * NB + b) * OUTW + G3;
            cr0 = row[n0r >> 1]; cr1 = row[n0z >> 1]; cr2 = row[n0n >> 1];
          }
        } else {
          Ar = ar0; Az = ar1; An = ar2;
          if ((t & 3) == 0 && t + 1 < LSEQ) {
            int need = t + 5; if (need > LSEQ) need = LSEQ;
            if (fvH < need) { while (ldflag(fHp) < need) {} }
            fvH = ldflag(fHp);
          }
          if (t + 1 < LSEQ) {
            const float* slot = &Aring[((size_t)((t + 1) & (NRING - 1))) * RINGSTRIDE +
                                       (size_t)abase * 225 + j];
            ar0 = ldg_dev(slot);
            ar1 = ldg_dev(slot + NH);
            ar2 = ldg_dev(slot + 2 * NH);
          }
        }

        float rg = sigm(Ar + Br);
        float zg = sigm(Az + Bz);
        float ng = tanh_f(An + rg * Bn);
        float hn = (1.f - zg) * ng + zg * hreg;
        hreg = hn;
        h16[(t + 1) & 1][j] = (_Float16)hn;
        hh0 = ((t & 3) == 0) ? hn : hh0;
        hh1 = ((t & 3) == 1) ? hn : hh1;
        hh2 = ((t & 3) == 2) ? hn : hh2;
        if ((t & 3) == 3) {
          float* base = out + (size_t)(t - 3) * NB * OUTW + (size_t)b * OUTW + c * NH + j;
          stg_dev(base, hh0);
          stg_dev(base + (size_t)NB * OUTW, hh1);
          stg_dev(base + 2 * (size_t)NB * OUTW, hh2);
          stg_dev(base + 3 * (size_t)NB * OUTW, hn);
          // newest in-flight: 3 prefetch loads + these 4 stores = 7 ->
          // vmcnt(7) confirms all OLDER store batches retired (lag-4 publish
          // provides the real margin; this is belt-and-suspenders).
          asm volatile("s_waitcnt vmcnt(7)" ::: "memory");
        }
      }
      if (tid == 0 && (t & 3) == 0 && t >= 8) stflag(&flags[c * NB + b], t - 4);
      WG_BARRIER();  // single barrier per step (h16 handoff, double-buffered)
    }
    __syncthreads();
    if (tid == 0) stflag(&flags[c * NB + b], LSEQ);
  } else {
    // ================= HELPER ROLE: A(t) = b_ih + U.x(t) (unchanged) =================
    const int hidx = bi - 144;
    const int hc = 2 + hidx / NB, b = hidx % NB;
    const int l = hc >> 1;
    const int ci = (l - 1) * 2 + (hc & 1);
    const int u0 = (l - 1) * 2;

    h8 Ua0 = zero8(), Ua1 = zero8(), Ua2 = zero8(), Ua3 = zero8(), Ua4 = zero8();
    h8 Ua5 = zero8(), Ua6 = zero8(), Ua7 = zero8(), Ua8 = zero8(), Ua9 = zero8();
    h8 Ua10 = zero8(), Ua11 = zero8(), Ua12 = zero8(), Ua13 = zero8(), Ua14 = zero8();
    h8 Ua15 = zero8(), Ua16 = zero8(), Ua17 = zero8(), Ua18 = zero8();
    float biha = 0.f;
    if (tid < G3) {
      const float* uA = w_ih12 + (size_t)(ci * G3 + tid) * (2 * NH);
      Ua0 = ld8f(uA, 0, 150);   Ua1 = ld8f(uA, 8, 150);   Ua2 = ld8f(uA, 16, 150);
      Ua3 = ld8f(uA, 24, 150);  Ua4 = ld8f(uA, 32, 150);  Ua5 = ld8f(uA, 40, 150);
      Ua6 = ld8f(uA, 48, 150);  Ua7 = ld8f(uA, 56, 150);  Ua8 = ld8f(uA, 64, 150);
      Ua9 = ld8f(uA, 72, 150);  Ua10 = ld8f(uA, 80, 150); Ua11 = ld8f(uA, 88, 150);
      Ua12 = ld8f(uA, 96, 150); Ua13 = ld8f(uA, 104, 150); Ua14 = ld8f(uA, 112, 150);
      Ua15 = ld8f(uA, 120, 150); Ua16 = ld8f(uA, 128, 150); Ua17 = ld8f(uA, 136, 150);
      Ua18 = ld8f(uA, 144, 150);
      biha = b_ih12[ci * G3 + tid];
    }
    if (tid < 2) { xs[tid][150] = (_Float16)0; xs[tid][151] = (_Float16)0; }

    const int* f0p = &flags[u0 * NB + b];
    const int* f1p = &flags[(u0 + 1) * NB + b];
    const int* pPp = &flags[hc * NB + b];
    int* fHo = &flags[144 + (hc - 2) * NB + b];
    const int abase = (hc - 2) * NB + b;
    int fu0 = 0, fu1 = 0, fvP = 0;
    float xpA = 0.f, xpB = 0.f;

    while (ldflag(f0p) < 2 || ldflag(f1p) < 2) {}
    if (tid < 150) {
      const float* xrow = out + (size_t)b * OUTW + u0 * NH + tid;
      xpA = ldg_dev(xrow);
      xpB = ldg_dev(xrow + (size_t)NB * OUTW);
    }
    __syncthreads();

    for (int t = 0; t < LSEQ; t++) {
      if (tid < 150) xs[t & 1][tid] = (_Float16)((t & 1) ? xpB : xpA);
      if ((t & 3) == 0) {
        if (t + 2 < LSEQ) {
          int need = t + 6; if (need > LSEQ) need = LSEQ;
          if (fu0 < need || fu1 < need) {
            while (ldflag(f0p) < need || ldflag(f1p) < need) {}
          }
        }
        if (t >= 24) {
          int needP = t - 20;
          if (fvP < needP) { while (ldflag(pPp) < needP) {} }
        }
        fu0 = ldflag(f0p); fu1 = ldflag(f1p); fvP = ldflag(pPp);
      }
      if (tid < 150 && t + 2 < LSEQ) {
        float v = ldg_dev(&out[(size_t)(t + 2) * NB * OUTW + (size_t)b * OUTW + u0 * NH + tid]);
        if (t & 1) xpB = v; else xpA = v;
      }
      WG_BARRIER();
      if (tid == 0 && (t & 3) == 0 && t >= 4) stflag(fHo, t);
      if (tid < G3) {
        PIN4(Ua0, Ua1, Ua2, Ua3); PIN4(Ua4, Ua5, Ua6, Ua7); PIN4(Ua8, Ua9, Ua10, Ua11);
        PIN4(Ua12, Ua13, Ua14, Ua15); PIN2(Ua16, Ua17); asm("" : "+v"(Ua18));
        const h8* xv = (const h8*)xs[t & 1];
        h8 X0 = xv[0], X1 = xv[1], X2 = xv[2], X3 = xv[3], X4 = xv[4];
        h8 X5 = xv[5], X6 = xv[6], X7 = xv[7], X8 = xv[8], X9 = xv[9];
        h8 X10 = xv[10], X11 = xv[11], X12 = xv[12], X13 = xv[13], X14 = xv[14];
        h8 X15 = xv[15], X16 = xv[16], X17 = xv[17], X18 = xv[18];
        float a0a = dot8(Ua0, X0, biha), a0b = dot8(Ua1, X1, 0.f);
        a0a = dot8(Ua2, X2, a0a);   a0b = dot8(Ua3, X3, a0b);
        a0a = dot8(Ua4, X4, a0a);   a0b = dot8(Ua5, X5, a0b);
        a0a = dot8(Ua6, X6, a0a);   a0b = dot8(Ua7, X7, a0b);
        a0a = dot8(Ua8, X8, a0a);   a0b = dot8(Ua9, X9, a0b);
        a0a = dot8(Ua10, X10, a0a); a0b = dot8(Ua11, X11, a0b);
        a0a = dot8(Ua12, X12, a0a); a0b = dot8(Ua13, X13, a0b);
        a0a = dot8(Ua14, X14, a0a); a0b = dot8(Ua15, X15, a0b);
        a0a = dot8(Ua16, X16, a0a); a0b = dot8(Ua17, X17, a0b);
        a0a = dot8(Ua18, X18, a0a);
        float val = a0a + a0b;
        stg_dev(&Aring[(t & (NRING - 1)) * RINGSTRIDE + abase * 225 + tid], val);
      }
      if ((t & 3) == 3) asm volatile("s_waitcnt vmcnt(0)" ::: "memory");
    }
    asm volatile("s_waitcnt vmcnt(0)" ::: "memory");
    __syncthreads();
    if (tid == 0) stflag(fHo, LSEQ);
  }
}

extern "C" void kernel_launch(void* const* d_in, const int* in_sizes, int n_in,
                              void* d_out, int out_size, void* d_ws, size_t ws_size,
                              hipStream_t stream) {
  const float* x      = (const float*)d_in[0];
  const float* h0     = (const float*)d_in[1];
  const float* w_ih0  = (const float*)d_in[2];
  const float* w_hh0  = (const float*)d_in[3];
  const float* b_ih0  = (const float*)d_in[4];
  const float* b_hh0  = (const float*)d_in[5];
  const float* w_ih12 = (const float*)d_in[6];
  const float* w_hh12 = (const float*)d_in[7];
  const float* b_ih12 = (const float*)d_in[8];
  const float* b_hh12 = (const float*)d_in[9];
  float* out = (float*)d_out;
  int* flags = (int*)d_ws;

  hipLaunchKernelGGL(init_flags, dim3(1), dim3(256), 0, stream, flags);
  hipLaunchKernelGGL(gemm_gx, dim3(768), dim3(256), 0, stream, x, w_ih0, b_ih0, out);
  hipLaunchKernelGGL(scan_gru, dim3(240), dim3(256), 0, stream,
                     h0, w_hh0, b_hh0, w_ih12, w_hh12, b_ih12, b_hh12, out, flags);
}